// Round 9
// baseline (238.063 us; speedup 1.0000x reference)
//
#include <hip/hip_runtime.h>

#define NSEQ 2048
#define DIM  512
#define KVBLK 32
#define NKT  64                    // 2048 / 32
#define TILEB 32768                // 32*512*2 bytes (bf16 tile)
#define SMEMB (2 * TILEB + 4096)   // V0,V1 + 4x1KB per-wave P-lds (68KB)

typedef __bf16 bf16x8 __attribute__((ext_vector_type(8)));
typedef float  f32x4  __attribute__((ext_vector_type(4)));

__device__ __forceinline__ void gld16(const void* g, void* l) {
  __builtin_amdgcn_global_load_lds(
      (const __attribute__((address_space(1))) unsigned int*)g,
      (__attribute__((address_space(3))) unsigned int*)l, 16, 0, 0);
}

// ---------- pre-pass: K -> bf16, per-tile [32 kv][512 d], byte ^= ((row&7)<<4)
// (kept swizzled; main kernel reads back with the same XOR — bijective, harmless)
__global__ __launch_bounds__(256) void prep_k(const float* __restrict__ ks,
                                              char* __restrict__ kp) {
  int b = blockIdx.x >> 6, kt = blockIdx.x & 63;
  int t = threadIdx.x;
  const float* src = ks + ((size_t)(b * NSEQ + kt * KVBLK)) * DIM;
  char* dst = kp + ((size_t)(b * 64 + kt)) * TILEB;
#pragma unroll
  for (int i = 0; i < 8; ++i) {
    int c = t + i * 256;
    int row = c >> 6;
    int d0 = (c & 63) * 8;
    const float4* s4 = (const float4*)(src + row * DIM + d0);
    float4 x = s4[0], y = s4[1];
    bf16x8 h;
    h[0] = (__bf16)x.x; h[1] = (__bf16)x.y; h[2] = (__bf16)x.z; h[3] = (__bf16)x.w;
    h[4] = (__bf16)y.x; h[5] = (__bf16)y.y; h[6] = (__bf16)y.z; h[7] = (__bf16)y.w;
    *(bf16x8*)(dst + row * 1024 + ((d0 * 2) ^ ((row & 7) << 4))) = h;
  }
}

// ---------- pre-pass: V -> bf16 transposed per tile (verified layout):
// byte(d,kv) = (d>>1)*128 + ((((d&1)*64) + kv*2) ^ (((d>>1)&7)<<4))
__global__ __launch_bounds__(256) void prep_v(const float* __restrict__ vs,
                                              char* __restrict__ vtp) {
  __shared__ __align__(16) char lds[TILEB];
  int b = blockIdx.x >> 6, kt = blockIdx.x & 63;
  int t = threadIdx.x;
  const float* src = vs + ((size_t)(b * NSEQ + kt * KVBLK)) * DIM;
#pragma unroll
  for (int i = 0; i < 8; ++i) {
    int c = t + i * 256;
    int kv = c >> 6;
    int d0 = (c & 63) * 8;
    const float4* s4 = (const float4*)(src + kv * DIM + d0);
    float4 x = s4[0], y = s4[1];
    float vals[8] = {x.x, x.y, x.z, x.w, y.x, y.y, y.z, y.w};
#pragma unroll
    for (int j = 0; j < 8; ++j) {
      int d = d0 + j;
      int byte = (d >> 1) * 128 + (((((d & 1) * 64) + kv * 2)) ^ (((d >> 1) & 7) << 4));
      *(__bf16*)(lds + byte) = (__bf16)vals[j];
    }
  }
  __syncthreads();
  char* dst = vtp + ((size_t)(b * 64 + kt)) * TILEB;
#pragma unroll
  for (int i = 0; i < 8; ++i) {
    int c16 = t + i * 256;
    *(bf16x8*)(dst + c16 * 16) = *(const bf16x8*)(lds + c16 * 16);
  }
}

// load one K chunk (k-steps kk2, kk2+1; lo and hi kv halves) from GLOBAL
#define LDK(dst, base, kk2)                                                     \
  dst[0] = *(const bf16x8*)((base) + (((kk2) * 64 + g * 16) ^ csw));            \
  dst[1] = *(const bf16x8*)((base) + 16384 + (((kk2) * 64 + g * 16) ^ csw));    \
  dst[2] = *(const bf16x8*)((base) + ((((kk2) + 1) * 64 + g * 16) ^ csw));      \
  dst[3] = *(const bf16x8*)((base) + 16384 + ((((kk2) + 1) * 64 + g * 16) ^ csw));

// ---------- main: 4 independent waves x 16q; K read direct from global (L2),
// V via LDS dbuf; pipelined PV(t) || QK(t+1); lane-local softmax; P roundtrip
__global__ __launch_bounds__(256) void attn_main(
    const float* __restrict__ qs, const char* __restrict__ kp,
    const char* __restrict__ vtp, const float* __restrict__ scale,
    float* __restrict__ out) {
  extern __shared__ __align__(16) char smem[];
  int b  = blockIdx.x & 7;          // batch -> XCD (L2 locality)
  int qt = blockIdx.x >> 3;
  int tid = threadIdx.x;
  int w = tid >> 6, lane = tid & 63;
  int c = lane & 15, g = lane >> 4;
  int q0 = qt * 64 + w * 16;

  char* vbuf = smem;                // + (i&1)*TILEB
  char* plds = smem + 2 * TILEB + w * 1024;

  float cc = 1.4426950408889634f / scale[0];   // log2(e)/scale folded into Q

  // Q fragments (B-operand for swapped QK; lane holds Q[q=c][k*32+g*8..+7])
  bf16x8 qf[16];
#pragma unroll
  for (int k = 0; k < 16; ++k) {
    int d = k * 32 + g * 8;
    const float4* p = (const float4*)(qs + ((size_t)(b * NSEQ + q0 + c)) * DIM + d);
    float4 x = p[0], y = p[1];
    float vals[8] = {x.x, x.y, x.z, x.w, y.x, y.y, y.z, y.w};
    bf16x8 h;
#pragma unroll
    for (int j = 0; j < 8; ++j) {
      float mlt = (d + j == 0) ? cc : -cc;     // Minkowski sign fold
      h[j] = (__bf16)(vals[j] * mlt);
    }
    qf[k] = h;
  }

  f32x4 acc[32];
#pragma unroll
  for (int i = 0; i < 32; ++i) acc[i] = (f32x4){0.f, 0.f, 0.f, 0.f};
  float mrow = -1e30f;               // running max for q=c (lane-local)

  const char* kpb = kp  + (size_t)b * 64 * TILEB;
  const char* vpb = vtp + (size_t)b * 64 * TILEB;

  const int csw = (c & 7) << 4;                // K swizzle term
  const int vt_lane = (c >> 1) * 128 +
      (((((c & 1) * 64) + g * 16)) ^ (((c >> 1) & 7) << 4));  // V/P A-frag read
  const int qb = (c >> 1) * 128;               // P write-side (q=c per lane)
  const int qh = (c & 1) * 64;
  const int qx = ((c >> 1) & 7) << 4;

  // prologue: stage V(0) via DMA; K(0) read from global, pipelined with QK(0)
#pragma unroll
  for (int i = 0; i < 8; ++i) {
    int o = tid * 16 + i * 4096;
    gld16(vpb + o, vbuf + o);
  }

  f32x4 sl, sh;
  bf16x8 pf;
  bf16x8 kf[2][4];

  {
    const char* kt0 = kpb + c * 1024;   // tile 0, this lane's lo-row base
    f32x4 sa0 = {0.f,0.f,0.f,0.f}, sb0 = {0.f,0.f,0.f,0.f};
    f32x4 sa1 = {0.f,0.f,0.f,0.f}, sb1 = {0.f,0.f,0.f,0.f};
    LDK(kf[0], kt0, 0)
#pragma unroll
    for (int kk = 0; kk < 8; ++kk) {
      if (kk < 7) { LDK(kf[(kk + 1) & 1], kt0, 2 * kk + 2) }
      sa0 = __builtin_amdgcn_mfma_f32_16x16x32_bf16(kf[kk & 1][0], qf[2 * kk], sa0, 0, 0, 0);
      sa1 = __builtin_amdgcn_mfma_f32_16x16x32_bf16(kf[kk & 1][1], qf[2 * kk], sa1, 0, 0, 0);
      sb0 = __builtin_amdgcn_mfma_f32_16x16x32_bf16(kf[kk & 1][2], qf[2 * kk + 1], sb0, 0, 0, 0);
      sb1 = __builtin_amdgcn_mfma_f32_16x16x32_bf16(kf[kk & 1][3], qf[2 * kk + 1], sb1, 0, 0, 0);
    }
    sl = sa0 + sb0; sh = sa1 + sb1;
    float mm = fmaxf(fmaxf(fmaxf(sl[0], sl[1]), fmaxf(sl[2], sl[3])),
                     fmaxf(fmaxf(sh[0], sh[1]), fmaxf(sh[2], sh[3])));
    mm = fmaxf(mm, __shfl_xor(mm, 16));
    mm = fmaxf(mm, __shfl_xor(mm, 32));
    mrow = mm;
#pragma unroll
    for (int r = 0; r < 4; ++r) {
      float pvl = exp2f(sl[r] - mrow);
      float pvh = exp2f(sh[r] - mrow);
      int kvl = 4 * g + r;
      *(__bf16*)(plds + qb + ((qh + kvl * 2) ^ qx))        = (__bf16)pvl;
      *(__bf16*)(plds + qb + ((qh + (16 + kvl) * 2) ^ qx)) = (__bf16)pvh;
    }
    pf = *(const bf16x8*)(plds + vt_lane);
  }
  __syncthreads();   // V(0) DMA drained (vmcnt(0) before barrier)

  // ---- main loop: iter t stages V(t+1), computes PV(t) || QK(t+1)
  for (int t = 0; t < NKT - 1; ++t) {
    {
      const char* vsrc = vpb + (size_t)(t + 1) * TILEB;
      char* vdst = vbuf + ((t + 1) & 1) * TILEB;
#pragma unroll
      for (int i = 0; i < 8; ++i) {
        int o = tid * 16 + i * 4096;
        gld16(vsrc + o, vdst + o);
      }
    }

    const char* kt1 = kpb + (size_t)(t + 1) * TILEB + c * 1024;  // K(t+1) lane base
    const char* vr  = vbuf + (t & 1) * TILEB + vt_lane;

    f32x4 sa0 = {0.f,0.f,0.f,0.f}, sb0 = {0.f,0.f,0.f,0.f};
    f32x4 sa1 = {0.f,0.f,0.f,0.f}, sb1 = {0.f,0.f,0.f,0.f};
    LDK(kf[0], kt1, 0)
#pragma unroll
    for (int kk = 0; kk < 8; ++kk) {
      if (kk < 7) { LDK(kf[(kk + 1) & 1], kt1, 2 * kk + 2) }
      // 4 PV MFMA (dtl = 4kk..4kk+3) — covers K-load latency
      bf16x8 vf0 = *(const bf16x8*)(vr + (4 * kk + 0) * 1024);
      bf16x8 vf1 = *(const bf16x8*)(vr + (4 * kk + 1) * 1024);
      bf16x8 vf2 = *(const bf16x8*)(vr + (4 * kk + 2) * 1024);
      bf16x8 vf3 = *(const bf16x8*)(vr + (4 * kk + 3) * 1024);
      acc[4 * kk + 0] = __builtin_amdgcn_mfma_f32_16x16x32_bf16(pf, vf0, acc[4 * kk + 0], 0, 0, 0);
      acc[4 * kk + 1] = __builtin_amdgcn_mfma_f32_16x16x32_bf16(pf, vf1, acc[4 * kk + 1], 0, 0, 0);
      acc[4 * kk + 2] = __builtin_amdgcn_mfma_f32_16x16x32_bf16(pf, vf2, acc[4 * kk + 2], 0, 0, 0);
      acc[4 * kk + 3] = __builtin_amdgcn_mfma_f32_16x16x32_bf16(pf, vf3, acc[4 * kk + 3], 0, 0, 0);
      // 4 QK MFMA consuming chunk kk
      sa0 = __builtin_amdgcn_mfma_f32_16x16x32_bf16(kf[kk & 1][0], qf[2 * kk], sa0, 0, 0, 0);
      sa1 = __builtin_amdgcn_mfma_f32_16x16x32_bf16(kf[kk & 1][1], qf[2 * kk], sa1, 0, 0, 0);
      sb0 = __builtin_amdgcn_mfma_f32_16x16x32_bf16(kf[kk & 1][2], qf[2 * kk + 1], sb0, 0, 0, 0);
      sb1 = __builtin_amdgcn_mfma_f32_16x16x32_bf16(kf[kk & 1][3], qf[2 * kk + 1], sb1, 0, 0, 0);
    }
    sl = sa0 + sb0; sh = sa1 + sb1;

    // ---- softmax(t+1) (lane-local row q=c; reduce over g only)
    float mm = fmaxf(fmaxf(fmaxf(sl[0], sl[1]), fmaxf(sl[2], sl[3])),
                     fmaxf(fmaxf(sh[0], sh[1]), fmaxf(sh[2], sh[3])));
    mm = fmaxf(mm, __shfl_xor(mm, 16));
    mm = fmaxf(mm, __shfl_xor(mm, 32));
    if (__any(mm > mrow + 11.0f)) {          // defer-max (2^11 headroom)
      float mn = fmaxf(mrow, mm);
      float f = exp2f(mrow - mn);
      mrow = mn;
      float f0 = __shfl(f, 4 * g + 0), f1 = __shfl(f, 4 * g + 1);
      float f2 = __shfl(f, 4 * g + 2), f3 = __shfl(f, 4 * g + 3);
#pragma unroll
      for (int i = 0; i < 32; ++i) {
        acc[i][0] *= f0; acc[i][1] *= f1; acc[i][2] *= f2; acc[i][3] *= f3;
      }
    }

    // ---- P(t+1) write + A-frag read (per-wave LDS, no barrier needed)
#pragma unroll
    for (int r = 0; r < 4; ++r) {
      float pvl = exp2f(sl[r] - mrow);
      float pvh = exp2f(sh[r] - mrow);
      int kvl = 4 * g + r;
      *(__bf16*)(plds + qb + ((qh + kvl * 2) ^ qx))        = (__bf16)pvl;
      *(__bf16*)(plds + qb + ((qh + (16 + kvl) * 2) ^ qx)) = (__bf16)pvh;
    }
    pf = *(const bf16x8*)(plds + vt_lane);

    __syncthreads();   // V(t+1) staged; all waves done reading vbuf[t&1]
  }

  // ---- tail: PV(NKT-1)
  {
    const char* vr = vbuf + ((NKT - 1) & 1) * TILEB + vt_lane;
#pragma unroll
    for (int dtl = 0; dtl < 32; ++dtl) {
      bf16x8 vf = *(const bf16x8*)(vr + dtl * 1024);
      acc[dtl] = __builtin_amdgcn_mfma_f32_16x16x32_bf16(pf, vf, acc[dtl], 0, 0, 0);
    }
  }

  // ---- epilogue: Lorentz normalization (softmax denom cancels; EPS preserved)
#pragma unroll
  for (int r = 0; r < 4; ++r) {
    float ss = 0.f;
#pragma unroll
    for (int dtl = 0; dtl < 32; ++dtl) ss += acc[dtl][r] * acc[dtl][r];
    ss += __shfl_xor(ss, 1);
    ss += __shfl_xor(ss, 2);
    ss += __shfl_xor(ss, 4);
    ss += __shfl_xor(ss, 8);
    float a0 = __shfl(acc[0][r], lane & 48);   // lane c==0 holds O[q][0]
    float d2 = fabsf(2.f * a0 * a0 - ss);
    float inv = rsqrtf(fmaxf(d2, 1e-8f));
    float* orow = out + ((size_t)(b * NSEQ + q0 + 4 * g + r)) * DIM + c;
#pragma unroll
    for (int dtl = 0; dtl < 32; ++dtl) orow[dtl * 16] = acc[dtl][r] * inv;
  }
}

extern "C" void kernel_launch(void* const* d_in, const int* in_sizes, int n_in,
                              void* d_out, int out_size, void* d_ws, size_t ws_size,
                              hipStream_t stream) {
  (void)in_sizes; (void)n_in; (void)out_size;
  const float* qs = (const float*)d_in[0];
  const float* ks = (const float*)d_in[1];
  const float* vs = (const float*)d_in[2];
  const float* scale = (const float*)d_in[3];
  // d_in[4] (bias) is uniform across softmax axis -> invariant -> unused
  float* out = (float*)d_out;

  size_t need = (size_t)2 * 8 * 64 * TILEB;   // 33.5 MB
  if (ws_size < need) return;
  char* kp  = (char*)d_ws;
  char* vtp = (char*)d_ws + (size_t)8 * 64 * TILEB;

  hipFuncSetAttribute((const void*)attn_main,
                      hipFuncAttributeMaxDynamicSharedMemorySize, SMEMB);

  prep_k<<<512, 256, 0, stream>>>(ks, kp);
  prep_v<<<512, 256, 0, stream>>>(vs, vtp);
  attn_main<<<256, 256, SMEMB, stream>>>(qs, kp, vtp, scale, out);
}

// Round 10
// 154.933 us; speedup vs baseline: 1.5366x; 1.5366x over previous
//
#include <hip/hip_runtime.h>

#define NSEQ 2048
#define DIM  512
#define KVBLK 32
#define NKT  64                    // total kv tiles
#define NIT  32                    // iters per wave (kv-half)
#define TILEB 32768                // 32*512*2 bytes
#define SMEMB_A (4 * TILEB + 8192) // K(2 streams) + V(2 streams) + 4x2KB P
#define SMEMB_4 (4 * TILEB + 4096) // R5 fallback layout

typedef __bf16 bf16x8 __attribute__((ext_vector_type(8)));
typedef float  f32x4  __attribute__((ext_vector_type(4)));

__device__ __forceinline__ void gld16(const void* g, void* l) {
  __builtin_amdgcn_global_load_lds(
      (const __attribute__((address_space(1))) unsigned int*)g,
      (__attribute__((address_space(3))) unsigned int*)l, 16, 0, 0);
}

// ---------- pre-pass: K -> bf16, per-tile [32 kv][512 d], byte ^= ((row&7)<<4)
__global__ __launch_bounds__(256) void prep_k(const float* __restrict__ ks,
                                              char* __restrict__ kp) {
  int b = blockIdx.x >> 6, kt = blockIdx.x & 63;
  int t = threadIdx.x;
  const float* src = ks + ((size_t)(b * NSEQ + kt * KVBLK)) * DIM;
  char* dst = kp + ((size_t)(b * 64 + kt)) * TILEB;
#pragma unroll
  for (int i = 0; i < 8; ++i) {
    int c = t + i * 256;
    int row = c >> 6;
    int d0 = (c & 63) * 8;
    const float4* s4 = (const float4*)(src + row * DIM + d0);
    float4 x = s4[0], y = s4[1];
    bf16x8 h;
    h[0] = (__bf16)x.x; h[1] = (__bf16)x.y; h[2] = (__bf16)x.z; h[3] = (__bf16)x.w;
    h[4] = (__bf16)y.x; h[5] = (__bf16)y.y; h[6] = (__bf16)y.z; h[7] = (__bf16)y.w;
    *(bf16x8*)(dst + row * 1024 + ((d0 * 2) ^ ((row & 7) << 4))) = h;
  }
}

// ---------- pre-pass: V -> bf16 transposed per tile (verified layout)
__global__ __launch_bounds__(256) void prep_v(const float* __restrict__ vs,
                                              char* __restrict__ vtp) {
  __shared__ __align__(16) char lds[TILEB];
  int b = blockIdx.x >> 6, kt = blockIdx.x & 63;
  int t = threadIdx.x;
  const float* src = vs + ((size_t)(b * NSEQ + kt * KVBLK)) * DIM;
#pragma unroll
  for (int i = 0; i < 8; ++i) {
    int c = t + i * 256;
    int kv = c >> 6;
    int d0 = (c & 63) * 8;
    const float4* s4 = (const float4*)(src + kv * DIM + d0);
    float4 x = s4[0], y = s4[1];
    float vals[8] = {x.x, x.y, x.z, x.w, y.x, y.y, y.z, y.w};
#pragma unroll
    for (int j = 0; j < 8; ++j) {
      int d = d0 + j;
      int byte = (d >> 1) * 128 + (((((d & 1) * 64) + kv * 2)) ^ (((d >> 1) & 7) << 4));
      *(__bf16*)(lds + byte) = (__bf16)vals[j];
    }
  }
  __syncthreads();
  char* dst = vtp + ((size_t)(b * 64 + kt)) * TILEB;
#pragma unroll
  for (int i = 0; i < 8; ++i) {
    int c16 = t + i * 256;
    *(bf16x8*)(dst + c16 * 16) = *(const bf16x8*)(lds + c16 * 16);
  }
}

#define MFMA __builtin_amdgcn_mfma_f32_16x16x32_bf16

// ---------- Scheme A: 4 waves = 2 q-sets(32q) x 2 kv-halves, single-buffered
// K/V streams with phase-split staging, per-wave independent chain, end merge.
__global__
__attribute__((amdgpu_flat_work_group_size(256, 256)))
__attribute__((amdgpu_waves_per_eu(1, 1)))
void attn_mainA(const float* __restrict__ qs, const char* __restrict__ kp,
                const char* __restrict__ vtp, const float* __restrict__ scale,
                float* __restrict__ out) {
  extern __shared__ __align__(16) char smem[];
  int b  = blockIdx.x & 7;           // batch -> XCD
  int qt = blockIdx.x >> 3;          // 0..31
  int tid = threadIdx.x;
  int w = tid >> 6, lane = tid & 63;
  int qs2 = w & 1, kvh = w >> 1;     // q-set, kv-half
  int c = lane & 15, g = lane >> 4;
  int q0 = qt * 64 + qs2 * 32;

  char* kbuf = smem + kvh * TILEB;
  char* vbuf = smem + 2 * TILEB + kvh * TILEB;
  char* plds = smem + 4 * TILEB + w * 2048;

  float cc = 1.4426950408889634f / scale[0];   // log2(e)/scale folded into Q

  // Q fragments for both 16-row groups (B-operand of swapped QK)
  bf16x8 qfA[16], qfB[16];
#pragma unroll
  for (int k = 0; k < 16; ++k) {
    int d = k * 32 + g * 8;
#pragma unroll
    for (int grp = 0; grp < 2; ++grp) {
      int row = q0 + grp * 16 + c;
      const float4* p = (const float4*)(qs + ((size_t)(b * NSEQ + row)) * DIM + d);
      float4 x = p[0], y = p[1];
      float vals[8] = {x.x, x.y, x.z, x.w, y.x, y.y, y.z, y.w};
      bf16x8 h;
#pragma unroll
      for (int j = 0; j < 8; ++j) {
        float mlt = (d + j == 0) ? cc : -cc;   // Minkowski sign fold
        h[j] = (__bf16)(vals[j] * mlt);
      }
      if (grp == 0) qfA[k] = h; else qfB[k] = h;
    }
  }

  f32x4 accA[32], accB[32];
#pragma unroll
  for (int i = 0; i < 32; ++i) { accA[i] = (f32x4){0,0,0,0}; accB[i] = (f32x4){0,0,0,0}; }
  float mrowA = -1e30f, mrowB = -1e30f;

  const char* kS0 = kp  + (size_t)b * 64 * TILEB;            // stream 0: tiles 0..31
  const char* kS1 = kS0 + (size_t)32 * TILEB;                // stream 1: tiles 32..63
  const char* vS0 = vtp + (size_t)b * 64 * TILEB;
  const char* vS1 = vS0 + (size_t)32 * TILEB;

  const int csw = (c & 7) << 4;
  const int vt_lane = (c >> 1) * 128 +
      (((((c & 1) * 64) + g * 16)) ^ (((c >> 1) & 7) << 4));
  const int qb = (c >> 1) * 128;
  const int qh = (c & 1) * 64;
  const int qx = ((c >> 1) & 7) << 4;

  // prologue: stage K(0) + V(0) for both streams
#pragma unroll
  for (int i = 0; i < 8; ++i) {
    int o = tid * 16 + i * 4096;
    gld16(kS0 + o, smem + o);
    gld16(kS1 + o, smem + TILEB + o);
    gld16(vS0 + o, smem + 2 * TILEB + o);
    gld16(vS1 + o, smem + 3 * TILEB + o);
  }
  __syncthreads();

  const char* krl = kbuf + c * 1024;
  const char* vr  = vbuf + vt_lane;

  for (int t = 0; t < NIT; ++t) {
    // ---- QK(t): own stream tile, both q-groups share K frags
    f32x4 sAl = {0,0,0,0}, sAh = {0,0,0,0}, sBl = {0,0,0,0}, sBh = {0,0,0,0};
#pragma unroll
    for (int k = 0; k < 16; ++k) {
      int bir = (k * 64 + g * 16) ^ csw;
      bf16x8 kfl = *(const bf16x8*)(krl + bir);
      bf16x8 kfh = *(const bf16x8*)(krl + 16384 + bir);
      sAl = MFMA(kfl, qfA[k], sAl, 0, 0, 0);
      sBl = MFMA(kfl, qfB[k], sBl, 0, 0, 0);
      sAh = MFMA(kfh, qfA[k], sAh, 0, 0, 0);
      sBh = MFMA(kfh, qfB[k], sBh, 0, 0, 0);
    }
    __syncthreads();                 // barrier A: K-buf free; V(t) DMA drained
    if (t + 1 < NIT) {               // stage K(t+1) both streams (drains by barrier B)
      size_t off = (size_t)(t + 1) * TILEB;
#pragma unroll
      for (int i = 0; i < 8; ++i) {
        int o = tid * 16 + i * 4096;
        gld16(kS0 + off + o, smem + o);
        gld16(kS1 + off + o, smem + TILEB + o);
      }
    }

    // ---- softmax both groups (lane-local row q; reduce over g only)
    float mmA = fmaxf(fmaxf(fmaxf(sAl[0], sAl[1]), fmaxf(sAl[2], sAl[3])),
                      fmaxf(fmaxf(sAh[0], sAh[1]), fmaxf(sAh[2], sAh[3])));
    float mmB = fmaxf(fmaxf(fmaxf(sBl[0], sBl[1]), fmaxf(sBl[2], sBl[3])),
                      fmaxf(fmaxf(sBh[0], sBh[1]), fmaxf(sBh[2], sBh[3])));
    mmA = fmaxf(mmA, __shfl_xor(mmA, 16)); mmA = fmaxf(mmA, __shfl_xor(mmA, 32));
    mmB = fmaxf(mmB, __shfl_xor(mmB, 16)); mmB = fmaxf(mmB, __shfl_xor(mmB, 32));
    bool grow = (mmA > mrowA + 11.0f) || (mmB > mrowB + 11.0f);
    if (__any(grow)) {
      float MA = fmaxf(mrowA, mmA), MB = fmaxf(mrowB, mmB);
      float fA = exp2f(mrowA - MA), fB = exp2f(mrowB - MB);
      mrowA = MA; mrowB = MB;
      float fA0 = __shfl(fA, 4*g+0), fA1 = __shfl(fA, 4*g+1);
      float fA2 = __shfl(fA, 4*g+2), fA3 = __shfl(fA, 4*g+3);
      float fB0 = __shfl(fB, 4*g+0), fB1 = __shfl(fB, 4*g+1);
      float fB2 = __shfl(fB, 4*g+2), fB3 = __shfl(fB, 4*g+3);
#pragma unroll
      for (int i = 0; i < 32; ++i) {
        accA[i][0] *= fA0; accA[i][1] *= fA1; accA[i][2] *= fA2; accA[i][3] *= fA3;
        accB[i][0] *= fB0; accB[i][1] *= fB1; accB[i][2] *= fB2; accB[i][3] *= fB3;
      }
    }
#pragma unroll
    for (int r = 0; r < 4; ++r) {
      int kvl = 4 * g + r;
      float pAl = exp2f(sAl[r] - mrowA), pAh = exp2f(sAh[r] - mrowA);
      float pBl = exp2f(sBl[r] - mrowB), pBh = exp2f(sBh[r] - mrowB);
      *(__bf16*)(plds + qb + ((qh + kvl * 2) ^ qx))               = (__bf16)pAl;
      *(__bf16*)(plds + qb + ((qh + (16 + kvl) * 2) ^ qx))        = (__bf16)pAh;
      *(__bf16*)(plds + 1024 + qb + ((qh + kvl * 2) ^ qx))        = (__bf16)pBl;
      *(__bf16*)(plds + 1024 + qb + ((qh + (16 + kvl) * 2) ^ qx)) = (__bf16)pBh;
    }
    bf16x8 pfA = *(const bf16x8*)(plds + vt_lane);
    bf16x8 pfB = *(const bf16x8*)(plds + 1024 + vt_lane);

    // ---- PV(t): each V frag feeds both q-groups
#pragma unroll
    for (int dtl = 0; dtl < 32; ++dtl) {
      bf16x8 vf = *(const bf16x8*)(vr + dtl * 1024);
      accA[dtl] = MFMA(pfA, vf, accA[dtl], 0, 0, 0);
      accB[dtl] = MFMA(pfB, vf, accB[dtl], 0, 0, 0);
    }
    __syncthreads();                 // barrier B: V-buf free; K(t+1) DMA drained
    if (t + 1 < NIT) {               // stage V(t+1) both streams (drains by barrier A)
      size_t off = (size_t)(t + 1) * TILEB;
#pragma unroll
      for (int i = 0; i < 8; ++i) {
        int o = tid * 16 + i * 4096;
        gld16(vS0 + off + o, smem + 2 * TILEB + o);
        gld16(vS1 + off + o, smem + 3 * TILEB + o);
      }
    }
  }

  // ---- merge kv-halves: share m via plds, rescale, combine via dead K/V LDS
  if (g == 0) {
    *(float*)(plds + c * 4)      = mrowA;
    *(float*)(plds + 64 + c * 4) = mrowB;
  }
  __syncthreads();
  {
    const char* pp = smem + 4 * TILEB + ((1 - kvh) * 2 + qs2) * 2048;
    float mpA = *(const float*)(pp + c * 4);
    float mpB = *(const float*)(pp + 64 + c * 4);
    float fA = exp2f(mrowA - fmaxf(mrowA, mpA));
    float fB = exp2f(mrowB - fmaxf(mrowB, mpB));
    float fA0 = __shfl(fA, 4*g+0), fA1 = __shfl(fA, 4*g+1);
    float fA2 = __shfl(fA, 4*g+2), fA3 = __shfl(fA, 4*g+3);
    float fB0 = __shfl(fB, 4*g+0), fB1 = __shfl(fB, 4*g+1);
    float fB2 = __shfl(fB, 4*g+2), fB3 = __shfl(fB, 4*g+3);
#pragma unroll
    for (int i = 0; i < 32; ++i) {
      accA[i][0] *= fA0; accA[i][1] *= fA1; accA[i][2] *= fA2; accA[i][3] *= fA3;
      accB[i][0] *= fB0; accB[i][1] *= fB1; accB[i][2] *= fB2; accB[i][3] *= fB3;
    }
  }
  if (kvh == 1) {
    char* mg = smem + qs2 * 65536;
#pragma unroll
    for (int i = 0; i < 32; ++i) *(f32x4*)(mg + i * 1024 + lane * 16) = accA[i];
#pragma unroll
    for (int i = 0; i < 32; ++i) *(f32x4*)(mg + 32768 + i * 1024 + lane * 16) = accB[i];
  }
  __syncthreads();
  if (kvh == 0) {
    const char* mg = smem + qs2 * 65536;
#pragma unroll
    for (int i = 0; i < 32; ++i) accA[i] += *(const f32x4*)(mg + i * 1024 + lane * 16);
#pragma unroll
    for (int i = 0; i < 32; ++i) accB[i] += *(const f32x4*)(mg + 32768 + i * 1024 + lane * 16);

    // ---- Lorentz normalization + store, both groups
#pragma unroll
    for (int grp = 0; grp < 2; ++grp) {
      f32x4* acc = grp ? accB : accA;
      int qg = q0 + grp * 16;
#pragma unroll
      for (int r = 0; r < 4; ++r) {
        float ss = 0.f;
#pragma unroll
        for (int dtl = 0; dtl < 32; ++dtl) ss += acc[dtl][r] * acc[dtl][r];
        ss += __shfl_xor(ss, 1);
        ss += __shfl_xor(ss, 2);
        ss += __shfl_xor(ss, 4);
        ss += __shfl_xor(ss, 8);
        float a0 = __shfl(acc[0][r], lane & 48);
        float d2 = fabsf(2.f * a0 * a0 - ss);
        float inv = rsqrtf(fmaxf(d2, 1e-8f));
        float* orow = out + ((size_t)(b * NSEQ + qg + 4 * g + r)) * DIM + c;
#pragma unroll
        for (int dtl = 0; dtl < 32; ++dtl) orow[dtl * 16] = acc[dtl][r] * inv;
      }
    }
  }
}

// ---------- fallback: R5-proven 4-wave 16q kernel (152 us)
__global__ __launch_bounds__(256) void attn_main4(
    const float* __restrict__ qs, const char* __restrict__ kp,
    const char* __restrict__ vtp, const float* __restrict__ scale,
    float* __restrict__ out) {
  extern __shared__ __align__(16) char smem[];
  int b  = blockIdx.x & 7;
  int qt = blockIdx.x >> 3;
  int tid = threadIdx.x;
  int w = tid >> 6, lane = tid & 63;
  int c = lane & 15, g = lane >> 4;
  int q0 = qt * 64 + w * 16;

  char* kbuf = smem;
  char* vbuf = smem + 2 * TILEB;
  char* plds = smem + 4 * TILEB + w * 1024;

  float cc = 1.4426950408889634f / scale[0];

  bf16x8 qf[16];
#pragma unroll
  for (int k = 0; k < 16; ++k) {
    int d = k * 32 + g * 8;
    const float4* p = (const float4*)(qs + ((size_t)(b * NSEQ + q0 + c)) * DIM + d);
    float4 x = p[0], y = p[1];
    float vals[8] = {x.x, x.y, x.z, x.w, y.x, y.y, y.z, y.w};
    bf16x8 h;
#pragma unroll
    for (int j = 0; j < 8; ++j) {
      float mlt = (d + j == 0) ? cc : -cc;
      h[j] = (__bf16)(vals[j] * mlt);
    }
    qf[k] = h;
  }

  f32x4 acc[32];
#pragma unroll
  for (int i = 0; i < 32; ++i) acc[i] = (f32x4){0.f, 0.f, 0.f, 0.f};
  float mrow = -1e30f;

  const char* kpb = kp  + (size_t)b * 64 * TILEB;
  const char* vpb = vtp + (size_t)b * 64 * TILEB;

  const int csw = (c & 7) << 4;
  const int vt_lane = (c >> 1) * 128 +
      (((((c & 1) * 64) + g * 16)) ^ (((c >> 1) & 7) << 4));
  const int qb = (c >> 1) * 128;
  const int qh = (c & 1) * 64;
  const int qx = ((c >> 1) & 7) << 4;

#pragma unroll
  for (int i = 0; i < 8; ++i) {
    int o = tid * 16 + i * 4096;
    gld16(kpb + o, kbuf + o);
    gld16(vpb + o, vbuf + o);
    gld16(kpb + TILEB + o, kbuf + TILEB + o);
  }
  __syncthreads();

  f32x4 sl, sh;
  bf16x8 pf;
  {
    f32x4 sa0 = {0,0,0,0}, sb0 = {0,0,0,0}, sa1 = {0,0,0,0}, sb1 = {0,0,0,0};
    const char* krl = kbuf + c * 1024;
    const char* krh = krl + 16 * 1024;
#pragma unroll
    for (int k = 0; k < 16; ++k) {
      int bir = (k * 64 + g * 16) ^ csw;
      bf16x8 kfl = *(const bf16x8*)(krl + bir);
      bf16x8 kfh = *(const bf16x8*)(krh + bir);
      if (k & 1) {
        sb0 = MFMA(kfl, qf[k], sb0, 0, 0, 0);
        sb1 = MFMA(kfh, qf[k], sb1, 0, 0, 0);
      } else {
        sa0 = MFMA(kfl, qf[k], sa0, 0, 0, 0);
        sa1 = MFMA(kfh, qf[k], sa1, 0, 0, 0);
      }
    }
    sl = sa0 + sb0; sh = sa1 + sb1;
    float mm = fmaxf(fmaxf(fmaxf(sl[0], sl[1]), fmaxf(sl[2], sl[3])),
                     fmaxf(fmaxf(sh[0], sh[1]), fmaxf(sh[2], sh[3])));
    mm = fmaxf(mm, __shfl_xor(mm, 16));
    mm = fmaxf(mm, __shfl_xor(mm, 32));
    mrow = mm;
#pragma unroll
    for (int r = 0; r < 4; ++r) {
      float pvl = exp2f(sl[r] - mrow);
      float pvh = exp2f(sh[r] - mrow);
      int kvl = 4 * g + r;
      *(__bf16*)(plds + qb + ((qh + kvl * 2) ^ qx))        = (__bf16)pvl;
      *(__bf16*)(plds + qb + ((qh + (16 + kvl) * 2) ^ qx)) = (__bf16)pvh;
    }
    pf = *(const bf16x8*)(plds + vt_lane);
  }
  __syncthreads();

  for (int t = 0; t < NKT - 1; ++t) {
    if (t + 2 < NKT) {
      const char* ksrc = kpb + (size_t)(t + 2) * TILEB;
      char* kdst = kbuf + (t & 1) * TILEB;
#pragma unroll
      for (int i = 0; i < 8; ++i) {
        int o = tid * 16 + i * 4096;
        gld16(ksrc + o, kdst + o);
      }
    }
    {
      const char* vsrc = vpb + (size_t)(t + 1) * TILEB;
      char* vdst = vbuf + ((t + 1) & 1) * TILEB;
#pragma unroll
      for (int i = 0; i < 8; ++i) {
        int o = tid * 16 + i * 4096;
        gld16(vsrc + o, vdst + o);
      }
    }
    f32x4 sa0 = {0,0,0,0}, sb0 = {0,0,0,0}, sa1 = {0,0,0,0}, sb1 = {0,0,0,0};
    const char* krl = kbuf + ((t + 1) & 1) * TILEB + c * 1024;
    const char* krh = krl + 16 * 1024;
    const char* vr  = vbuf + (t & 1) * TILEB + vt_lane;
#pragma unroll
    for (int k = 0; k < 16; ++k) {
      int bir = (k * 64 + g * 16) ^ csw;
      bf16x8 kfl = *(const bf16x8*)(krl + bir);
      bf16x8 kfh = *(const bf16x8*)(krh + bir);
      bf16x8 vf0 = *(const bf16x8*)(vr + (2 * k) * 1024);
      bf16x8 vf1 = *(const bf16x8*)(vr + (2 * k + 1) * 1024);
      if (k & 1) {
        sb0 = MFMA(kfl, qf[k], sb0, 0, 0, 0);
        sb1 = MFMA(kfh, qf[k], sb1, 0, 0, 0);
      } else {
        sa0 = MFMA(kfl, qf[k], sa0, 0, 0, 0);
        sa1 = MFMA(kfh, qf[k], sa1, 0, 0, 0);
      }
      acc[2 * k]     = MFMA(pf, vf0, acc[2 * k], 0, 0, 0);
      acc[2 * k + 1] = MFMA(pf, vf1, acc[2 * k + 1], 0, 0, 0);
    }
    sl = sa0 + sb0; sh = sa1 + sb1;

    float mm = fmaxf(fmaxf(fmaxf(sl[0], sl[1]), fmaxf(sl[2], sl[3])),
                     fmaxf(fmaxf(sh[0], sh[1]), fmaxf(sh[2], sh[3])));
    mm = fmaxf(mm, __shfl_xor(mm, 16));
    mm = fmaxf(mm, __shfl_xor(mm, 32));
    if (__any(mm > mrow + 11.0f)) {
      float mn = fmaxf(mrow, mm);
      float f = exp2f(mrow - mn);
      mrow = mn;
      float f0 = __shfl(f, 4 * g + 0), f1 = __shfl(f, 4 * g + 1);
      float f2 = __shfl(f, 4 * g + 2), f3 = __shfl(f, 4 * g + 3);
#pragma unroll
      for (int i = 0; i < 32; ++i) {
        acc[i][0] *= f0; acc[i][1] *= f1; acc[i][2] *= f2; acc[i][3] *= f3;
      }
    }
#pragma unroll
    for (int r = 0; r < 4; ++r) {
      float pvl = exp2f(sl[r] - mrow);
      float pvh = exp2f(sh[r] - mrow);
      int kvl = 4 * g + r;
      *(__bf16*)(plds + qb + ((qh + kvl * 2) ^ qx))        = (__bf16)pvl;
      *(__bf16*)(plds + qb + ((qh + (16 + kvl) * 2) ^ qx)) = (__bf16)pvh;
    }
    pf = *(const bf16x8*)(plds + vt_lane);
    __syncthreads();
  }
  {
    const char* vr = vbuf + ((NKT - 1) & 1) * TILEB + vt_lane;
#pragma unroll
    for (int dtl = 0; dtl < 32; ++dtl) {
      bf16x8 vf = *(const bf16x8*)(vr + dtl * 1024);
      acc[dtl] = MFMA(pf, vf, acc[dtl], 0, 0, 0);
    }
  }
#pragma unroll
  for (int r = 0; r < 4; ++r) {
    float ss = 0.f;
#pragma unroll
    for (int dtl = 0; dtl < 32; ++dtl) ss += acc[dtl][r] * acc[dtl][r];
    ss += __shfl_xor(ss, 1);
    ss += __shfl_xor(ss, 2);
    ss += __shfl_xor(ss, 4);
    ss += __shfl_xor(ss, 8);
    float a0 = __shfl(acc[0][r], lane & 48);
    float d2 = fabsf(2.f * a0 * a0 - ss);
    float inv = rsqrtf(fmaxf(d2, 1e-8f));
    float* orow = out + ((size_t)(b * NSEQ + q0 + 4 * g + r)) * DIM + c;
#pragma unroll
    for (int dtl = 0; dtl < 32; ++dtl) orow[dtl * 16] = acc[dtl][r] * inv;
  }
}

extern "C" void kernel_launch(void* const* d_in, const int* in_sizes, int n_in,
                              void* d_out, int out_size, void* d_ws, size_t ws_size,
                              hipStream_t stream) {
  (void)in_sizes; (void)n_in; (void)out_size;
  const float* qs = (const float*)d_in[0];
  const float* ks = (const float*)d_in[1];
  const float* vs = (const float*)d_in[2];
  const float* scale = (const float*)d_in[3];
  float* out = (float*)d_out;

  size_t need = (size_t)2 * 8 * 64 * TILEB;
  if (ws_size < need) return;
  char* kp  = (char*)d_ws;
  char* vtp = (char*)d_ws + (size_t)8 * 64 * TILEB;

  prep_k<<<512, 256, 0, stream>>>(ks, kp);
  prep_v<<<512, 256, 0, stream>>>(vs, vtp);

  // use the 32q kernel only if it compiled spill-free (deterministic host query)
  hipFuncAttributes aA;
  bool useA = false;
  if (hipFuncGetAttributes(&aA, (const void*)attn_mainA) == hipSuccess)
    useA = (aA.localSizeBytes == 0);

  if (useA) {
    hipFuncSetAttribute((const void*)attn_mainA,
                        hipFuncAttributeMaxDynamicSharedMemorySize, SMEMB_A);
    attn_mainA<<<256, 256, SMEMB_A, stream>>>(qs, kp, vtp, scale, out);
  } else {
    hipFuncSetAttribute((const void*)attn_main4,
                        hipFuncAttributeMaxDynamicSharedMemorySize, SMEMB_4);
    attn_main4<<<256, 256, SMEMB_4, stream>>>(qs, kp, vtp, scale, out);
  }
}